// Round 9
// baseline (268.702 us; speedup 1.0000x reference)
//
#include <hip/hip_runtime.h>
#include <hip/hip_bf16.h>

#define D 128

typedef short short8 __attribute__((ext_vector_type(8)));
typedef float f32x4  __attribute__((ext_vector_type(4)));

__device__ __forceinline__ float lo_bf(unsigned u) { return __uint_as_float(u << 16); }
__device__ __forceinline__ float hi_bf(unsigned u) { return __uint_as_float(u & 0xFFFF0000u); }

// ---------------- Stage 0: wsplit + zero degs (fused, replaces memset) ----------------
__global__ void wsplit_zero(const float* __restrict__ W, short* __restrict__ whi,
                            short* __restrict__ wlo, int* __restrict__ degs, int N) {
    int i = blockIdx.x * blockDim.x + threadIdx.x;
    if (i < D * D) {
        float w = W[i];
        unsigned u = __float_as_uint(w);
        float hi = __uint_as_float(u & 0xFFFF0000u);
        float lo = w - hi;
        whi[i] = (short)(u >> 16);
        wlo[i] = (short)(__float_as_uint(lo) >> 16);
    }
    for (int j = i; j < N; j += gridDim.x * blockDim.x) degs[j] = 0;
}

// ---------------- Stage 1: in-degrees (8 edges/thread) ----------------
__global__ void deg_kernel(const int* __restrict__ dst, int* __restrict__ degs, int E) {
    int i = blockIdx.x * blockDim.x + threadIdx.x;
    int E8 = E >> 3;
    if (i < E8) {
        int4 a = ((const int4*)dst)[2 * i];
        int4 b = ((const int4*)dst)[2 * i + 1];
        atomicAdd(&degs[a.x], 1);
        atomicAdd(&degs[a.y], 1);
        atomicAdd(&degs[a.z], 1);
        atomicAdd(&degs[a.w], 1);
        atomicAdd(&degs[b.x], 1);
        atomicAdd(&degs[b.y], 1);
        atomicAdd(&degs[b.z], 1);
        atomicAdd(&degs[b.w], 1);
    }
    if (i < (E & 7)) atomicAdd(&degs[dst[(E & ~7) + i]], 1);
}

// ---------------- Stage 2a: per-block degree sums + norm ----------------
__global__ __launch_bounds__(256) void scan_blocks(
    const int* __restrict__ degs, int* __restrict__ blocksum,
    float* __restrict__ norm, int N)
{
    const int tid = threadIdx.x;
    const int i = blockIdx.x * 256 + tid;
    int d = (i < N) ? degs[i] : 0;
    if (i < N) norm[i] = rsqrtf((float)d + 1.0f);

    int v = d;
    #pragma unroll
    for (int o = 32; o > 0; o >>= 1) v += __shfl_down(v, o, 64);
    __shared__ int ws[4];
    if ((tid & 63) == 0) ws[tid >> 6] = v;
    __syncthreads();
    if (tid == 0) blocksum[blockIdx.x] = ws[0] + ws[1] + ws[2] + ws[3];
}

// ---------------- Stage 2b: final offsets (block sums scanned redundantly per block) ----------------
__global__ __launch_bounds__(256) void scan_final(
    const int* __restrict__ degs, const int* __restrict__ blocksum,
    int* __restrict__ off, int* __restrict__ cursor, int N, int E, int nb)
{
    __shared__ int s[256];
    const int tid = threadIdx.x;
    s[tid] = (tid < nb) ? blocksum[tid] : 0;
    __syncthreads();
    for (int o = 1; o < 256; o <<= 1) {
        int v = (tid >= o) ? s[tid - o] : 0;
        __syncthreads();
        s[tid] += v;
        __syncthreads();
    }
    const int boff = (blockIdx.x == 0) ? 0 : s[blockIdx.x - 1];

    const int i = blockIdx.x * 256 + tid;
    const int lane = tid & 63, w = tid >> 6;
    int d = (i < N) ? degs[i] : 0;

    int v = d;                                   // wave inclusive scan
    #pragma unroll
    for (int o = 1; o < 64; o <<= 1) {
        int t = __shfl_up(v, o, 64);
        if (lane >= o) v += t;
    }
    __shared__ int ws[4];
    if (lane == 63) ws[w] = v;
    __syncthreads();
    int woff = 0;
    #pragma unroll
    for (int k = 0; k < 4; ++k) if (k < w) woff += ws[k];

    int excl = boff + woff + v - d;
    if (i < N) { off[i] = excl; cursor[i] = excl; }
    if (blockIdx.x == 0 && tid == 0) off[N] = E;
}

// ---------------- Stage 3: fill CSR (packed src | et<<20), 8 edges/thread ----------------
__global__ void fill_kernel(const int* __restrict__ src, const int* __restrict__ dst,
                            const int* __restrict__ efeat, int* __restrict__ cursor,
                            unsigned* __restrict__ csr, int E) {
    int i = blockIdx.x * blockDim.x + threadIdx.x;
    int E8 = E >> 3;
    if (i < E8) {
        int4 da = ((const int4*)dst)[2 * i];
        int4 db = ((const int4*)dst)[2 * i + 1];
        int4 sa = ((const int4*)src)[2 * i];
        int4 sb = ((const int4*)src)[2 * i + 1];
        int4 ta = ((const int4*)efeat)[2 * i];
        int4 tb = ((const int4*)efeat)[2 * i + 1];
        int p0 = atomicAdd(&cursor[da.x], 1);
        int p1 = atomicAdd(&cursor[da.y], 1);
        int p2 = atomicAdd(&cursor[da.z], 1);
        int p3 = atomicAdd(&cursor[da.w], 1);
        int p4 = atomicAdd(&cursor[db.x], 1);
        int p5 = atomicAdd(&cursor[db.y], 1);
        int p6 = atomicAdd(&cursor[db.z], 1);
        int p7 = atomicAdd(&cursor[db.w], 1);
        csr[p0] = (unsigned)sa.x | ((unsigned)ta.x << 20);
        csr[p1] = (unsigned)sa.y | ((unsigned)ta.y << 20);
        csr[p2] = (unsigned)sa.z | ((unsigned)ta.z << 20);
        csr[p3] = (unsigned)sa.w | ((unsigned)ta.w << 20);
        csr[p4] = (unsigned)sb.x | ((unsigned)tb.x << 20);
        csr[p5] = (unsigned)sb.y | ((unsigned)tb.y << 20);
        csr[p6] = (unsigned)sb.z | ((unsigned)tb.z << 20);
        csr[p7] = (unsigned)sb.w | ((unsigned)tb.w << 20);
    }
    if (i < (E & 7)) {
        int e = (E & ~7) + i;
        int p = atomicAdd(&cursor[dst[e]], 1);
        csr[p] = (unsigned)src[e] | ((unsigned)efeat[e] << 20);
    }
}

// ---------------- Stage 4: h = x @ W^T + b via split-bf16 MFMA (f32-accurate) ----------------
__global__ __launch_bounds__(256) void h_mfma_kernel(
    const float* __restrict__ x, const short* __restrict__ whi, const short* __restrict__ wlo,
    const float* __restrict__ b, __hip_bfloat16* __restrict__ hbf, int N)
{
    const int lane = threadIdx.x & 63;
    const int wave = threadIdx.x >> 6;
    const int m0 = (blockIdx.x * 4 + wave) * 16;
    if (m0 >= N) return;
    const int row  = lane & 15;
    const int quad = lane >> 4;
    int mrow = m0 + row; if (mrow >= N) mrow = N - 1;   // safe dup for ragged tail

    f32x4 acc[8];
    #pragma unroll
    for (int t = 0; t < 8; ++t) acc[t] = (f32x4){0.f, 0.f, 0.f, 0.f};

    #pragma unroll
    for (int kk = 0; kk < 4; ++kk) {
        const int ko = kk * 32 + quad * 8;
        const float4* xp4 = (const float4*)(x + (size_t)mrow * D + ko);
        float4 xa = xp4[0], xb = xp4[1];
        float xv[8] = {xa.x, xa.y, xa.z, xa.w, xb.x, xb.y, xb.z, xb.w};
        short8 ahi, alo;
        #pragma unroll
        for (int j = 0; j < 8; ++j) {
            unsigned u = __float_as_uint(xv[j]);
            float hi = __uint_as_float(u & 0xFFFF0000u);
            float lo = xv[j] - hi;
            ahi[j] = (short)(u >> 16);
            alo[j] = (short)(__float_as_uint(lo) >> 16);
        }
        #pragma unroll
        for (int t = 0; t < 8; ++t) {
            const short8 bhi = *(const short8*)(whi + (size_t)(t * 16 + row) * D + ko);
            const short8 blo = *(const short8*)(wlo + (size_t)(t * 16 + row) * D + ko);
            acc[t] = __builtin_amdgcn_mfma_f32_16x16x32_bf16(ahi, bhi, acc[t], 0, 0, 0);
            acc[t] = __builtin_amdgcn_mfma_f32_16x16x32_bf16(ahi, blo, acc[t], 0, 0, 0);
            acc[t] = __builtin_amdgcn_mfma_f32_16x16x32_bf16(alo, bhi, acc[t], 0, 0, 0);
        }
    }

    #pragma unroll
    for (int t = 0; t < 8; ++t) {
        const int col = t * 16 + row;
        const float bias = b[col];
        #pragma unroll
        for (int r = 0; r < 4; ++r) {
            const int m = m0 + quad * 4 + r;
            if (m < N) hbf[(size_t)m * D + col] = __float2bfloat16(acc[t][r] + bias);
        }
    }
}

// ---------------- Stage 5: gather-aggregate, 8 edges/wave, bank-swizzled ee ----------------
// ee stored rotated: slot (c + 4*et) & 127 at pitch 136 (slots 128..135 duplicate the
// wrap) -> read bank = (12*et + 8*s + j) mod 32; 12*et mod 32 distinct for et mod 8
// -> near-uniform spread across the 8 edge-groups. Group g = lane>>3 handles one edge;
// sublane s = lane&7 covers channels {8s..8s+7, 64+8s..64+8s+7}.
#define EEP 136
__global__ __launch_bounds__(256) void agg_kernel(
    const int* __restrict__ off, const unsigned* __restrict__ csr,
    const float* __restrict__ norm, const uint4* __restrict__ hbf4,
    const float* __restrict__ ee, const float* __restrict__ res_w,
    float* __restrict__ out, int N)
{
    __shared__ float ees[16 * EEP];
    const int tid = threadIdx.x;
    for (int i = tid; i < 16 * EEP; i += 256) {
        int et = i / EEP, r = i - et * EEP;
        ees[i] = ee[et * 128 + ((r - 4 * et) & 127)];
    }
    __syncthreads();

    const int n = blockIdx.x * 4 + (tid >> 6);
    if (n >= N) return;
    const int lane = tid & 63;
    const int g = lane >> 3;     // 8 edge-groups
    const int s = lane & 7;      // 8 sublanes

    const int beg = off[n], end = off[n + 1];
    const int deg = end - beg;
    const float nd = norm[n];

    float acc[16];
    #pragma unroll
    for (int j = 0; j < 16; ++j) acc[j] = 0.f;

    for (int base = beg; base < end; base += 64) {
        int idx = base + lane;
        unsigned se = 0; float en = 0.f;
        if (idx < end) {
            se = csr[idx];
            en = norm[se & 0xFFFFF] * nd;
        }
        int cnt = end - base; if (cnt > 64) cnt = 64;
        #pragma unroll 2
        for (int j8 = 0; j8 < cnt; j8 += 8) {
            int sl = j8 + g;
            unsigned sej = (unsigned)__shfl((int)se, sl);
            float enj = __shfl(en, sl);               // lanes >= cnt carry en=0
            int sj  = sej & 0xFFFFF;
            int etj = sej >> 20;
            uint4 h0 = hbf4[(size_t)sj * 16 + s];
            uint4 h1 = hbf4[(size_t)sj * 16 + s + 8];
            const float* ebase = ees + etj * EEP;
            int o1 = (8 * s + 4 * etj) & 127;
            int o2 = (64 + 8 * s + 4 * etj) & 127;
            float4 ea = *(const float4*)(ebase + o1);
            float4 eb = *(const float4*)(ebase + o1 + 4);
            float4 ec = *(const float4*)(ebase + o2);
            float4 ed = *(const float4*)(ebase + o2 + 4);
            acc[0]  = fmaf(fmaxf(lo_bf(h0.x) + ea.x, 0.f), enj, acc[0]);
            acc[1]  = fmaf(fmaxf(hi_bf(h0.x) + ea.y, 0.f), enj, acc[1]);
            acc[2]  = fmaf(fmaxf(lo_bf(h0.y) + ea.z, 0.f), enj, acc[2]);
            acc[3]  = fmaf(fmaxf(hi_bf(h0.y) + ea.w, 0.f), enj, acc[3]);
            acc[4]  = fmaf(fmaxf(lo_bf(h0.z) + eb.x, 0.f), enj, acc[4]);
            acc[5]  = fmaf(fmaxf(hi_bf(h0.z) + eb.y, 0.f), enj, acc[5]);
            acc[6]  = fmaf(fmaxf(lo_bf(h0.w) + eb.z, 0.f), enj, acc[6]);
            acc[7]  = fmaf(fmaxf(hi_bf(h0.w) + eb.w, 0.f), enj, acc[7]);
            acc[8]  = fmaf(fmaxf(lo_bf(h1.x) + ec.x, 0.f), enj, acc[8]);
            acc[9]  = fmaf(fmaxf(hi_bf(h1.x) + ec.y, 0.f), enj, acc[9]);
            acc[10] = fmaf(fmaxf(lo_bf(h1.y) + ec.z, 0.f), enj, acc[10]);
            acc[11] = fmaf(fmaxf(hi_bf(h1.y) + ec.w, 0.f), enj, acc[11]);
            acc[12] = fmaf(fmaxf(lo_bf(h1.z) + ed.x, 0.f), enj, acc[12]);
            acc[13] = fmaf(fmaxf(hi_bf(h1.z) + ed.y, 0.f), enj, acc[13]);
            acc[14] = fmaf(fmaxf(lo_bf(h1.w) + ed.z, 0.f), enj, acc[14]);
            acc[15] = fmaf(fmaxf(hi_bf(h1.w) + ed.w, 0.f), enj, acc[15]);
        }
    }

    // reduce partial sums across the 8 groups (same s)
    #pragma unroll
    for (int j = 0; j < 16; ++j) {
        acc[j] += __shfl_xor(acc[j], 8, 64);
        acc[j] += __shfl_xor(acc[j], 16, 64);
        acc[j] += __shfl_xor(acc[j], 32, 64);
    }

    if (g == 0) {   // lanes 0..7
        uint4 hn0 = hbf4[(size_t)n * 16 + s];
        uint4 hn1 = hbf4[(size_t)n * 16 + s + 8];
        float invd = 1.0f / (float)(deg + 1);
        const float4* rwp = (const float4*)(res_w + 8 * s);
        float4 r0 = rwp[0], r1 = rwp[1];
        const float4* rwq = (const float4*)(res_w + 64 + 8 * s);
        float4 r2 = rwq[0], r3 = rwq[1];
        float4 o0, o1, o2, o3;
        o0.x = acc[0]  + fmaxf(lo_bf(hn0.x) + r0.x, 0.f) * invd;
        o0.y = acc[1]  + fmaxf(hi_bf(hn0.x) + r0.y, 0.f) * invd;
        o0.z = acc[2]  + fmaxf(lo_bf(hn0.y) + r0.z, 0.f) * invd;
        o0.w = acc[3]  + fmaxf(hi_bf(hn0.y) + r0.w, 0.f) * invd;
        o1.x = acc[4]  + fmaxf(lo_bf(hn0.z) + r1.x, 0.f) * invd;
        o1.y = acc[5]  + fmaxf(hi_bf(hn0.z) + r1.y, 0.f) * invd;
        o1.z = acc[6]  + fmaxf(lo_bf(hn0.w) + r1.z, 0.f) * invd;
        o1.w = acc[7]  + fmaxf(hi_bf(hn0.w) + r1.w, 0.f) * invd;
        o2.x = acc[8]  + fmaxf(lo_bf(hn1.x) + r2.x, 0.f) * invd;
        o2.y = acc[9]  + fmaxf(hi_bf(hn1.x) + r2.y, 0.f) * invd;
        o2.z = acc[10] + fmaxf(lo_bf(hn1.y) + r2.z, 0.f) * invd;
        o2.w = acc[11] + fmaxf(hi_bf(hn1.y) + r2.w, 0.f) * invd;
        o3.x = acc[12] + fmaxf(lo_bf(hn1.z) + r3.x, 0.f) * invd;
        o3.y = acc[13] + fmaxf(hi_bf(hn1.z) + r3.y, 0.f) * invd;
        o3.z = acc[14] + fmaxf(lo_bf(hn1.w) + r3.z, 0.f) * invd;
        o3.w = acc[15] + fmaxf(hi_bf(hn1.w) + r3.w, 0.f) * invd;
        float4* op = (float4*)(out + (size_t)n * D + 8 * s);
        op[0] = o0;
        op[1] = o1;
        float4* oq = (float4*)(out + (size_t)n * D + 64 + 8 * s);
        oq[0] = o2;
        oq[1] = o3;
    }
}

extern "C" void kernel_launch(void* const* d_in, const int* in_sizes, int n_in,
                              void* d_out, int out_size, void* d_ws, size_t ws_size,
                              hipStream_t stream) {
    const float* nfeat = (const float*)d_in[0];
    const int* efeat   = (const int*)d_in[1];
    const int* src     = (const int*)d_in[2];
    const int* dst     = (const int*)d_in[3];
    const float* W     = (const float*)d_in[4];
    const float* b     = (const float*)d_in[5];
    const float* ee    = (const float*)d_in[6];
    const float* res_w = (const float*)d_in[7];

    const int N = in_sizes[0] / D;
    const int E = in_sizes[2];
    const int nb = (N + 255) / 256;   // 196 <= 256

    // workspace: degs | off | cursor | norm | blocksum | csr | whi | wlo | hbf
    char* p = (char*)d_ws;
    int* degs      = (int*)p;      p += (size_t)N * 4;
    int* off       = (int*)p;      p += (size_t)(N + 1) * 4;
    int* cursor    = (int*)p;      p += (size_t)N * 4;
    float* norm    = (float*)p;    p += (size_t)N * 4;
    int* blocksum  = (int*)p;      p += 256 * 4;
    p = (char*)(((uintptr_t)p + 15) & ~(uintptr_t)15);
    unsigned* csr  = (unsigned*)p; p += (size_t)E * 4;
    p = (char*)(((uintptr_t)p + 15) & ~(uintptr_t)15);
    short* whi     = (short*)p;    p += (size_t)D * D * 2;
    short* wlo     = (short*)p;    p += (size_t)D * D * 2;
    p = (char*)(((uintptr_t)p + 15) & ~(uintptr_t)15);
    __hip_bfloat16* hbf = (__hip_bfloat16*)p;

    wsplit_zero<<<nb, 256, 0, stream>>>(W, whi, wlo, degs, N);

    const int E8 = (E + 7) >> 3;
    deg_kernel<<<(E8 + 255) / 256, 256, 0, stream>>>(dst, degs, E);
    scan_blocks<<<nb, 256, 0, stream>>>(degs, blocksum, norm, N);
    scan_final<<<nb, 256, 0, stream>>>(degs, blocksum, off, cursor, N, E, nb);
    fill_kernel<<<(E8 + 255) / 256, 256, 0, stream>>>(src, dst, efeat, cursor, csr, E);

    const int mtiles = (N + 15) / 16;
    h_mfma_kernel<<<(mtiles + 3) / 4, 256, 0, stream>>>(nfeat, whi, wlo, b, hbf, N);
    agg_kernel<<<(N + 3) / 4, 256, 0, stream>>>(off, csr, norm, (const uint4*)hbf,
                                                ee, res_w, (float*)d_out, N);
}

// Round 10
// 235.851 us; speedup vs baseline: 1.1393x; 1.1393x over previous
//
#include <hip/hip_runtime.h>
#include <hip/hip_bf16.h>

#define D 128

typedef short short8 __attribute__((ext_vector_type(8)));
typedef float f32x4  __attribute__((ext_vector_type(4)));

__device__ __forceinline__ float lo_bf(unsigned u) { return __uint_as_float(u << 16); }
__device__ __forceinline__ float hi_bf(unsigned u) { return __uint_as_float(u & 0xFFFF0000u); }

// ---------------- Stage 0: wsplit + zero degs ----------------
__global__ void wsplit_zero(const float* __restrict__ W, short* __restrict__ whi,
                            short* __restrict__ wlo, int* __restrict__ degs, int N) {
    int i = blockIdx.x * blockDim.x + threadIdx.x;
    if (i < D * D) {
        float w = W[i];
        unsigned u = __float_as_uint(w);
        float hi = __uint_as_float(u & 0xFFFF0000u);
        float lo = w - hi;
        whi[i] = (short)(u >> 16);
        wlo[i] = (short)(__float_as_uint(lo) >> 16);
    }
    for (int j = i; j < N; j += gridDim.x * blockDim.x) degs[j] = 0;
}

// ---------------- Stage 1: rank = per-dst arrival index (replaces deg pass) ----------------
// rank stored coalesced by edge id; degs ends up as final in-degree.
__global__ void rank_kernel(const int* __restrict__ dst, int* __restrict__ degs,
                            int* __restrict__ rank, int E) {
    int i = blockIdx.x * blockDim.x + threadIdx.x;
    int E4 = E >> 2;
    if (i < E4) {
        int4 d = ((const int4*)dst)[i];
        int4 r;
        r.x = atomicAdd(&degs[d.x], 1);
        r.y = atomicAdd(&degs[d.y], 1);
        r.z = atomicAdd(&degs[d.z], 1);
        r.w = atomicAdd(&degs[d.w], 1);
        ((int4*)rank)[i] = r;
    }
    if (i < (E & 3)) {
        int e = (E & ~3) + i;
        rank[e] = atomicAdd(&degs[dst[e]], 1);
    }
}

// ---------------- Stage 2a: per-block degree sums + norm ----------------
__global__ __launch_bounds__(256) void scan_blocks(
    const int* __restrict__ degs, int* __restrict__ blocksum,
    float* __restrict__ norm, int N)
{
    const int tid = threadIdx.x;
    const int i = blockIdx.x * 256 + tid;
    int d = (i < N) ? degs[i] : 0;
    if (i < N) norm[i] = rsqrtf((float)d + 1.0f);

    int v = d;
    #pragma unroll
    for (int o = 32; o > 0; o >>= 1) v += __shfl_down(v, o, 64);
    __shared__ int ws[4];
    if ((tid & 63) == 0) ws[tid >> 6] = v;
    __syncthreads();
    if (tid == 0) blocksum[blockIdx.x] = ws[0] + ws[1] + ws[2] + ws[3];
}

// ---------------- Stage 2b: final offsets (block sums scanned redundantly per block) ----------------
__global__ __launch_bounds__(256) void scan_final(
    const int* __restrict__ degs, const int* __restrict__ blocksum,
    int* __restrict__ off, int N, int E, int nb)
{
    __shared__ int s[256];
    const int tid = threadIdx.x;
    s[tid] = (tid < nb) ? blocksum[tid] : 0;
    __syncthreads();
    for (int o = 1; o < 256; o <<= 1) {
        int v = (tid >= o) ? s[tid - o] : 0;
        __syncthreads();
        s[tid] += v;
        __syncthreads();
    }
    const int boff = (blockIdx.x == 0) ? 0 : s[blockIdx.x - 1];

    const int i = blockIdx.x * 256 + tid;
    const int lane = tid & 63, w = tid >> 6;
    int d = (i < N) ? degs[i] : 0;

    int v = d;                                   // wave inclusive scan
    #pragma unroll
    for (int o = 1; o < 64; o <<= 1) {
        int t = __shfl_up(v, o, 64);
        if (lane >= o) v += t;
    }
    __shared__ int ws[4];
    if (lane == 63) ws[w] = v;
    __syncthreads();
    int woff = 0;
    #pragma unroll
    for (int k = 0; k < 4; ++k) if (k < w) woff += ws[k];

    int excl = boff + woff + v - d;
    if (i < N) off[i] = excl;
    if (blockIdx.x == 0 && tid == 0) off[N] = E;
}

// ---------------- Stage 3: scatter CSR (no atomics, fire-and-forget stores) ----------------
__global__ void scatter_kernel(const int* __restrict__ src, const int* __restrict__ dst,
                               const int* __restrict__ efeat, const int* __restrict__ rank,
                               const int* __restrict__ off, unsigned* __restrict__ csr, int E) {
    int i = blockIdx.x * blockDim.x + threadIdx.x;
    int E4 = E >> 2;
    if (i < E4) {
        int4 d = ((const int4*)dst)[i];
        int4 s = ((const int4*)src)[i];
        int4 t = ((const int4*)efeat)[i];
        int4 r = ((const int4*)rank)[i];
        int p0 = off[d.x] + r.x;
        int p1 = off[d.y] + r.y;
        int p2 = off[d.z] + r.z;
        int p3 = off[d.w] + r.w;
        csr[p0] = (unsigned)s.x | ((unsigned)t.x << 20);
        csr[p1] = (unsigned)s.y | ((unsigned)t.y << 20);
        csr[p2] = (unsigned)s.z | ((unsigned)t.z << 20);
        csr[p3] = (unsigned)s.w | ((unsigned)t.w << 20);
    }
    if (i < (E & 3)) {
        int e = (E & ~3) + i;
        csr[off[dst[e]] + rank[e]] = (unsigned)src[e] | ((unsigned)efeat[e] << 20);
    }
}

// ---------------- Stage 4: h = x @ W^T + b via split-bf16 MFMA (f32-accurate) ----------------
__global__ __launch_bounds__(256) void h_mfma_kernel(
    const float* __restrict__ x, const short* __restrict__ whi, const short* __restrict__ wlo,
    const float* __restrict__ b, __hip_bfloat16* __restrict__ hbf, int N)
{
    const int lane = threadIdx.x & 63;
    const int wave = threadIdx.x >> 6;
    const int m0 = (blockIdx.x * 4 + wave) * 16;
    if (m0 >= N) return;
    const int row  = lane & 15;
    const int quad = lane >> 4;
    int mrow = m0 + row; if (mrow >= N) mrow = N - 1;   // safe dup for ragged tail

    f32x4 acc[8];
    #pragma unroll
    for (int t = 0; t < 8; ++t) acc[t] = (f32x4){0.f, 0.f, 0.f, 0.f};

    #pragma unroll
    for (int kk = 0; kk < 4; ++kk) {
        const int ko = kk * 32 + quad * 8;
        const float4* xp4 = (const float4*)(x + (size_t)mrow * D + ko);
        float4 xa = xp4[0], xb = xp4[1];
        float xv[8] = {xa.x, xa.y, xa.z, xa.w, xb.x, xb.y, xb.z, xb.w};
        short8 ahi, alo;
        #pragma unroll
        for (int j = 0; j < 8; ++j) {
            unsigned u = __float_as_uint(xv[j]);
            float hi = __uint_as_float(u & 0xFFFF0000u);
            float lo = xv[j] - hi;
            ahi[j] = (short)(u >> 16);
            alo[j] = (short)(__float_as_uint(lo) >> 16);
        }
        #pragma unroll
        for (int t = 0; t < 8; ++t) {
            const short8 bhi = *(const short8*)(whi + (size_t)(t * 16 + row) * D + ko);
            const short8 blo = *(const short8*)(wlo + (size_t)(t * 16 + row) * D + ko);
            acc[t] = __builtin_amdgcn_mfma_f32_16x16x32_bf16(ahi, bhi, acc[t], 0, 0, 0);
            acc[t] = __builtin_amdgcn_mfma_f32_16x16x32_bf16(ahi, blo, acc[t], 0, 0, 0);
            acc[t] = __builtin_amdgcn_mfma_f32_16x16x32_bf16(alo, bhi, acc[t], 0, 0, 0);
        }
    }

    #pragma unroll
    for (int t = 0; t < 8; ++t) {
        const int col = t * 16 + row;
        const float bias = b[col];
        #pragma unroll
        for (int r = 0; r < 4; ++r) {
            const int m = m0 + quad * 4 + r;
            if (m < N) hbf[(size_t)m * D + col] = __float2bfloat16(acc[t][r] + bias);
        }
    }
}

// ---------------- Stage 5: gather-aggregate, 8 edges/wave (r8-exact, 57 us proven) ----------------
#define EEP 132
__global__ __launch_bounds__(256) void agg_kernel(
    const int* __restrict__ off, const unsigned* __restrict__ csr,
    const float* __restrict__ norm, const uint4* __restrict__ hbf4,
    const float* __restrict__ ee, const float* __restrict__ res_w,
    float* __restrict__ out, int N)
{
    __shared__ float ees[16 * EEP];
    const int tid = threadIdx.x;
    for (int i = tid; i < 16 * 128; i += 256) {
        int et = i >> 7, c = i & 127;
        ees[et * EEP + c] = ee[i];
    }
    __syncthreads();

    const int n = blockIdx.x * 4 + (tid >> 6);
    if (n >= N) return;
    const int lane = tid & 63;
    const int g = lane >> 3;     // 8 edge-groups
    const int s = lane & 7;      // 8 sublanes

    const int beg = off[n], end = off[n + 1];
    const int deg = end - beg;
    const float nd = norm[n];

    float acc[16];
    #pragma unroll
    for (int j = 0; j < 16; ++j) acc[j] = 0.f;

    for (int base = beg; base < end; base += 64) {
        int idx = base + lane;
        unsigned se = 0; float en = 0.f;
        if (idx < end) {
            se = csr[idx];
            en = norm[se & 0xFFFFF] * nd;
        }
        int cnt = end - base; if (cnt > 64) cnt = 64;
        #pragma unroll 2
        for (int j8 = 0; j8 < cnt; j8 += 8) {
            int sl = j8 + g;
            unsigned sej = (unsigned)__shfl((int)se, sl);
            float enj = __shfl(en, sl);               // lanes >= cnt carry en=0
            int sj  = sej & 0xFFFFF;
            int etj = sej >> 20;
            uint4 h0 = hbf4[(size_t)sj * 16 + s];
            uint4 h1 = hbf4[(size_t)sj * 16 + s + 8];
            const float* ep = ees + etj * EEP + 8 * s;
            float4 ea = *(const float4*)(ep);
            float4 eb = *(const float4*)(ep + 4);
            float4 ec = *(const float4*)(ep + 64);
            float4 ed = *(const float4*)(ep + 68);
            acc[0]  = fmaf(fmaxf(lo_bf(h0.x) + ea.x, 0.f), enj, acc[0]);
            acc[1]  = fmaf(fmaxf(hi_bf(h0.x) + ea.y, 0.f), enj, acc[1]);
            acc[2]  = fmaf(fmaxf(lo_bf(h0.y) + ea.z, 0.f), enj, acc[2]);
            acc[3]  = fmaf(fmaxf(hi_bf(h0.y) + ea.w, 0.f), enj, acc[3]);
            acc[4]  = fmaf(fmaxf(lo_bf(h0.z) + eb.x, 0.f), enj, acc[4]);
            acc[5]  = fmaf(fmaxf(hi_bf(h0.z) + eb.y, 0.f), enj, acc[5]);
            acc[6]  = fmaf(fmaxf(lo_bf(h0.w) + eb.z, 0.f), enj, acc[6]);
            acc[7]  = fmaf(fmaxf(hi_bf(h0.w) + eb.w, 0.f), enj, acc[7]);
            acc[8]  = fmaf(fmaxf(lo_bf(h1.x) + ec.x, 0.f), enj, acc[8]);
            acc[9]  = fmaf(fmaxf(hi_bf(h1.x) + ec.y, 0.f), enj, acc[9]);
            acc[10] = fmaf(fmaxf(lo_bf(h1.y) + ec.z, 0.f), enj, acc[10]);
            acc[11] = fmaf(fmaxf(hi_bf(h1.y) + ec.w, 0.f), enj, acc[11]);
            acc[12] = fmaf(fmaxf(lo_bf(h1.z) + ed.x, 0.f), enj, acc[12]);
            acc[13] = fmaf(fmaxf(hi_bf(h1.z) + ed.y, 0.f), enj, acc[13]);
            acc[14] = fmaf(fmaxf(lo_bf(h1.w) + ed.z, 0.f), enj, acc[14]);
            acc[15] = fmaf(fmaxf(hi_bf(h1.w) + ed.w, 0.f), enj, acc[15]);
        }
    }

    // reduce partial sums across the 8 groups (same s)
    #pragma unroll
    for (int j = 0; j < 16; ++j) {
        acc[j] += __shfl_xor(acc[j], 8, 64);
        acc[j] += __shfl_xor(acc[j], 16, 64);
        acc[j] += __shfl_xor(acc[j], 32, 64);
    }

    if (g == 0) {   // lanes 0..7
        uint4 hn0 = hbf4[(size_t)n * 16 + s];
        uint4 hn1 = hbf4[(size_t)n * 16 + s + 8];
        float invd = 1.0f / (float)(deg + 1);
        const float4* rwp = (const float4*)(res_w + 8 * s);
        float4 r0 = rwp[0], r1 = rwp[1];
        const float4* rwq = (const float4*)(res_w + 64 + 8 * s);
        float4 r2 = rwq[0], r3 = rwq[1];
        float4 o0, o1, o2, o3;
        o0.x = acc[0]  + fmaxf(lo_bf(hn0.x) + r0.x, 0.f) * invd;
        o0.y = acc[1]  + fmaxf(hi_bf(hn0.x) + r0.y, 0.f) * invd;
        o0.z = acc[2]  + fmaxf(lo_bf(hn0.y) + r0.z, 0.f) * invd;
        o0.w = acc[3]  + fmaxf(hi_bf(hn0.y) + r0.w, 0.f) * invd;
        o1.x = acc[4]  + fmaxf(lo_bf(hn0.z) + r1.x, 0.f) * invd;
        o1.y = acc[5]  + fmaxf(hi_bf(hn0.z) + r1.y, 0.f) * invd;
        o1.z = acc[6]  + fmaxf(lo_bf(hn0.w) + r1.z, 0.f) * invd;
        o1.w = acc[7]  + fmaxf(hi_bf(hn0.w) + r1.w, 0.f) * invd;
        o2.x = acc[8]  + fmaxf(lo_bf(hn1.x) + r2.x, 0.f) * invd;
        o2.y = acc[9]  + fmaxf(hi_bf(hn1.x) + r2.y, 0.f) * invd;
        o2.z = acc[10] + fmaxf(lo_bf(hn1.y) + r2.z, 0.f) * invd;
        o2.w = acc[11] + fmaxf(hi_bf(hn1.y) + r2.w, 0.f) * invd;
        o3.x = acc[12] + fmaxf(lo_bf(hn1.z) + r3.x, 0.f) * invd;
        o3.y = acc[13] + fmaxf(hi_bf(hn1.z) + r3.y, 0.f) * invd;
        o3.z = acc[14] + fmaxf(lo_bf(hn1.w) + r3.z, 0.f) * invd;
        o3.w = acc[15] + fmaxf(hi_bf(hn1.w) + r3.w, 0.f) * invd;
        float4* op = (float4*)(out + (size_t)n * D + 8 * s);
        op[0] = o0;
        op[1] = o1;
        float4* oq = (float4*)(out + (size_t)n * D + 64 + 8 * s);
        oq[0] = o2;
        oq[1] = o3;
    }
}

extern "C" void kernel_launch(void* const* d_in, const int* in_sizes, int n_in,
                              void* d_out, int out_size, void* d_ws, size_t ws_size,
                              hipStream_t stream) {
    const float* nfeat = (const float*)d_in[0];
    const int* efeat   = (const int*)d_in[1];
    const int* src     = (const int*)d_in[2];
    const int* dst     = (const int*)d_in[3];
    const float* W     = (const float*)d_in[4];
    const float* b     = (const float*)d_in[5];
    const float* ee    = (const float*)d_in[6];
    const float* res_w = (const float*)d_in[7];

    const int N = in_sizes[0] / D;
    const int E = in_sizes[2];
    const int nb = (N + 255) / 256;   // 196 <= 256

    // workspace: degs | off | norm | blocksum | rank | csr | whi | wlo | hbf
    char* p = (char*)d_ws;
    int* degs      = (int*)p;      p += (size_t)N * 4;
    int* off       = (int*)p;      p += (size_t)(N + 1) * 4;
    float* norm    = (float*)p;    p += (size_t)N * 4;
    int* blocksum  = (int*)p;      p += 256 * 4;
    p = (char*)(((uintptr_t)p + 15) & ~(uintptr_t)15);
    int* rank      = (int*)p;      p += (size_t)E * 4;
    unsigned* csr  = (unsigned*)p; p += (size_t)E * 4;
    short* whi     = (short*)p;    p += (size_t)D * D * 2;
    short* wlo     = (short*)p;    p += (size_t)D * D * 2;
    p = (char*)(((uintptr_t)p + 15) & ~(uintptr_t)15);
    __hip_bfloat16* hbf = (__hip_bfloat16*)p;

    wsplit_zero<<<nb, 256, 0, stream>>>(W, whi, wlo, degs, N);

    const int E4 = (E + 3) >> 2;
    rank_kernel<<<(E4 + 255) / 256, 256, 0, stream>>>(dst, degs, rank, E);
    scan_blocks<<<nb, 256, 0, stream>>>(degs, blocksum, norm, N);
    scan_final<<<nb, 256, 0, stream>>>(degs, blocksum, off, N, E, nb);
    scatter_kernel<<<(E4 + 255) / 256, 256, 0, stream>>>(src, dst, efeat, rank, off, csr, E);

    const int mtiles = (N + 15) / 16;
    h_mfma_kernel<<<(mtiles + 3) / 4, 256, 0, stream>>>(nfeat, whi, wlo, b, hbf, N);
    agg_kernel<<<(N + 3) / 4, 256, 0, stream>>>(off, csr, norm, (const uint4*)hbf,
                                                ee, res_w, (float*)d_out, N);
}